// Round 5
// baseline (454.912 us; speedup 1.0000x reference)
//
#include <hip/hip_runtime.h>
#include <hip/hip_bf16.h>
#include <stdint.h>

#define N_NODES  100000
#define N_PAD    100032          // padded to multiple of 64 for MLP tiles
#define N_EDGES  1600000
#define DIM      128
#define N_LAYERS 3
#define N_GRAPHS 2048

#define BSHIFT   8               // bucket = 256 consecutive dst nodes
#define NBUCKET  391             // ceil(N_NODES / 256)
#define P1CHUNK  4096
#define P1GRID   391             // ceil(N_EDGES / P1CHUNK)

typedef _Float16 f16;
typedef __attribute__((ext_vector_type(2))) _Float16 f16x2;
typedef __attribute__((ext_vector_type(4))) _Float16 f16x4;
typedef __attribute__((ext_vector_type(8))) _Float16 f16x8;
typedef __attribute__((ext_vector_type(4))) float f32x4;

#define MFMA16(a, b, c) __builtin_amdgcn_mfma_f32_16x16x32_f16((a), (b), (c), 0, 0, 0)

// ---------------- workspace layout (bytes, 64B-aligned) ----------------
#define OFF_OFFS  0u             // (N_NODES+1) ints
#define OFF_BHT   400064u        // NBUCKET ints (bucket totals)
#define OFF_BST   401664u        // NBUCKET+1 ints (bucket starts)
#define OFF_GCUR  403264u        // NBUCKET ints (bucket cursors)
#define OFF_BLKH  404864u        // P1GRID*NBUCKET ints (per-block bucket hist)
#define OFF_ESRC  1016448u       // N_EDGES ints
#define OFF_PAIR  7416448u       // N_EDGES u32 packed (src<<8 | d&255)
#define OFF_X16   13816448u      // N_PAD*DIM f16
#define OFF_A16   39424640u      // N_PAD*DIM f16
#define OFF_B16   65032832u      // N_PAD*DIM f16
#define OFF_W1T   90641024u      // 3*128*128 f16 ([l][n][k])
#define OFF_W2T   90739328u      // 3*128*128 f16
// end ~90.8 MB

// ---------------- CSR build: bucket partition ----------------

__global__ __launch_bounds__(256) void k_bhist(const int* __restrict__ dst,
                                               int* __restrict__ btot, int* __restrict__ blkh) {
    __shared__ int h[NBUCKET];
    int tid = threadIdx.x, b = blockIdx.x;
    for (int i = tid; i < NBUCKET; i += 256) h[i] = 0;
    __syncthreads();
    int base = b * P1CHUNK;
    int n = min(P1CHUNK, N_EDGES - base);
    for (int i = tid; i < n; i += 256)
        atomicAdd(&h[dst[base + i] >> BSHIFT], 1);
    __syncthreads();
    for (int i = tid; i < NBUCKET; i += 256) {
        blkh[b * NBUCKET + i] = h[i];
        atomicAdd(&btot[i], h[i]);
    }
}

__global__ void k_bscan(const int* __restrict__ btot, int* __restrict__ bstart,
                        int* __restrict__ gcursor, int* __restrict__ offs) {
    __shared__ int s[NBUCKET + 1];
    if (threadIdx.x == 0) {
        int run = 0;
        for (int i = 0; i < NBUCKET; i++) { s[i] = run; run += btot[i]; }
        s[NBUCKET] = run;
    }
    __syncthreads();
    int t = threadIdx.x;
    for (int i = t; i <= NBUCKET; i += 256) bstart[i] = s[i];
    for (int i = t; i < NBUCKET; i += 256)  gcursor[i] = s[i];
    if (t == 0) offs[N_NODES] = N_EDGES;
}

__global__ __launch_bounds__(256) void k_part1(const int* __restrict__ src, const int* __restrict__ dst,
                                               const int* __restrict__ blkh, int* __restrict__ gcursor,
                                               uint32_t* __restrict__ pairs) {
    __shared__ int gbase[NBUCKET];
    __shared__ int cur[NBUCKET];
    int tid = threadIdx.x, b = blockIdx.x;
    for (int i = tid; i < NBUCKET; i += 256) {
        int h = blkh[b * NBUCKET + i];
        gbase[i] = atomicAdd(&gcursor[i], h);
        cur[i] = 0;
    }
    __syncthreads();
    int base = b * P1CHUNK;
    int n = min(P1CHUNK, N_EDGES - base);
    for (int i = tid; i < n; i += 256) {
        int d = dst[base + i], s = src[base + i];
        int bin = d >> BSHIFT;
        int slot = atomicAdd(&cur[bin], 1);
        pairs[gbase[bin] + slot] = ((uint32_t)s << 8) | (uint32_t)(d & 255);
    }
}

__global__ __launch_bounds__(256) void k_part2(const uint32_t* __restrict__ pairs,
                                               const int* __restrict__ bstart,
                                               int* __restrict__ offs, int* __restrict__ esrc) {
    __shared__ int cnt[256];
    __shared__ int cur[256];
    __shared__ int sc[256];
    int t = threadIdx.x, b = blockIdx.x;
    int n0 = b << BSHIFT;
    int nn = min(256, N_NODES - n0);
    int e0 = bstart[b], e1 = bstart[b + 1];
    cnt[t] = 0;
    __syncthreads();
    for (int i = e0 + t; i < e1; i += 256)
        atomicAdd(&cnt[pairs[i] & 255], 1);
    __syncthreads();
    int my = cnt[t];
    sc[t] = my;
    __syncthreads();
    for (int off = 1; off < 256; off <<= 1) {
        int v = (t >= off) ? sc[t - off] : 0;
        __syncthreads();
        sc[t] += v;
        __syncthreads();
    }
    int excl = sc[t] - my;
    cur[t] = excl;
    if (t < nn) offs[n0 + t] = e0 + excl;
    __syncthreads();
    for (int i = e0 + t; i < e1; i += 256) {
        uint32_t p = pairs[i];
        int pos = e0 + atomicAdd(&cur[p & 255], 1);
        esrc[pos] = (int)(p >> 8);          // 16KB region, single block -> single XCD
    }
}

// ---------------- dtype conversion ----------------

__global__ void k_cvtX(const float* __restrict__ x, f16* __restrict__ o) {
    size_t i = ((size_t)blockIdx.x * 256 + threadIdx.x) * 8;
    float4 v0 = *(const float4*)&x[i];
    float4 v1 = *(const float4*)&x[i + 4];
    f16x8 h;
    h[0] = (f16)v0.x; h[1] = (f16)v0.y; h[2] = (f16)v0.z; h[3] = (f16)v0.w;
    h[4] = (f16)v1.x; h[5] = (f16)v1.y; h[6] = (f16)v1.z; h[7] = (f16)v1.w;
    *(f16x8*)&o[i] = h;
}

// W: [3][k][n] f32 -> Wt: [3][n][k] f16
__global__ void k_cvtW(const float* __restrict__ W, f16* __restrict__ Wt) {
    int t = blockIdx.x * 256 + threadIdx.x;
    int l = t >> 14;
    int kn = t & 16383;
    int k = kn >> 7, n = kn & 127;
    Wt[l * 16384 + n * 128 + k] = (f16)W[t];
}

// ---------------- fused layer: gather-agg -> LDS tile -> MLP -> global ----------------
// out = relu(relu((x_i + sum_j x_j) @ W1 + b1) @ W2 + b2)

#define BM 64
#define LDS_K 136    // padded row stride in f16 (272 B)

__global__ __launch_bounds__(256) void k_fused(
    const f16* __restrict__ xin, f16* __restrict__ xout,
    const int* __restrict__ offs, const int* __restrict__ esrc,
    const f16* __restrict__ W1t, const float* __restrict__ b1,
    const f16* __restrict__ W2t, const float* __restrict__ b2)
{
    __shared__ __align__(16) f16 tile[BM * LDS_K];
    int tid  = threadIdx.x;
    int lane = tid & 63;
    int w    = tid >> 6;          // wave 0..3
    int fr   = lane & 15;         // 0..15
    int fg   = lane >> 4;         // 0..3
    int row0 = blockIdx.x * BM;

    // ---- gather: wave w owns nodes row0+w*16 .. +15, serial; 64 lanes per node
    // (4 edge groups x 16 cols, 4-deep unroll = 16 loads in flight per wave)
    {
        int g = fg, c = fr;
        const f16x8* xr = (const f16x8*)xin;     // 16 x 16B chunks per row
        for (int s_ = 0; s_ < 16; s_++) {
            int node = row0 + w * 16 + s_;
            bool valid = node < N_NODES;
            int cl = valid ? node : 0;
            float acc[8];
            f16x8 sv = xr[(size_t)cl * 16 + c];
#pragma unroll
            for (int j = 0; j < 8; j++) acc[j] = (valid && g == 0) ? (float)sv[j] : 0.f;
            if (valid) {
                int e0 = offs[node], e1 = offs[node + 1];
                int e = e0 + g;
                for (; e + 12 < e1; e += 16) {
                    int s0 = esrc[e], s1 = esrc[e + 4], s2 = esrc[e + 8], s3 = esrc[e + 12];
                    f16x8 v0 = xr[(size_t)s0 * 16 + c];
                    f16x8 v1 = xr[(size_t)s1 * 16 + c];
                    f16x8 v2 = xr[(size_t)s2 * 16 + c];
                    f16x8 v3 = xr[(size_t)s3 * 16 + c];
#pragma unroll
                    for (int j = 0; j < 8; j++)
                        acc[j] += ((float)v0[j] + (float)v1[j]) + ((float)v2[j] + (float)v3[j]);
                }
                for (; e < e1; e += 4) {
                    f16x8 v = xr[(size_t)esrc[e] * 16 + c];
#pragma unroll
                    for (int j = 0; j < 8; j++) acc[j] += (float)v[j];
                }
            }
#pragma unroll
            for (int j = 0; j < 8; j++) {
                acc[j] += __shfl_xor(acc[j], 16);
                acc[j] += __shfl_xor(acc[j], 32);
            }
            if (g == 0) {
                f16x8 o;
#pragma unroll
                for (int j = 0; j < 8; j++) o[j] = (f16)acc[j];
                *(f16x8*)&tile[(w * 16 + s_) * LDS_K + c * 8] = o;
            }
        }
    }
    __syncthreads();

    // ---- GEMM1 (swapped operands -> H^T): lane holds H[n=w*32+nt*16+fg*4+r][m=mt*16+fr]
    f16x8 wf[2][4];
    float4 bv[2];
#pragma unroll
    for (int nt = 0; nt < 2; nt++) {
        int col = w * 32 + nt * 16 + fr;
#pragma unroll
        for (int ks = 0; ks < 4; ks++)
            wf[nt][ks] = *(const f16x8*)&W1t[col * DIM + ks * 32 + fg * 8];
        bv[nt] = *(const float4*)&b1[w * 32 + nt * 16 + fg * 4];
    }

    f32x4 acc[4][2];
#pragma unroll
    for (int mt = 0; mt < 4; mt++)
#pragma unroll
        for (int nt = 0; nt < 2; nt++) acc[mt][nt] = (f32x4){0.f, 0.f, 0.f, 0.f};

#pragma unroll
    for (int mt = 0; mt < 4; mt++)
#pragma unroll
        for (int ks = 0; ks < 4; ks++) {
            f16x8 a = *(const f16x8*)&tile[(mt * 16 + fr) * LDS_K + ks * 32 + fg * 8];
            acc[mt][0] = MFMA16(wf[0][ks], a, acc[mt][0]);
            acc[mt][1] = MFMA16(wf[1][ks], a, acc[mt][1]);
        }
    __syncthreads();   // all X reads done before overwriting tile with H

    // H epilogue: relu(acc+b1), 8B vector writes to tile[node][feature]
#pragma unroll
    for (int mt = 0; mt < 4; mt++)
#pragma unroll
        for (int nt = 0; nt < 2; nt++) {
            f16x4 hv;
            hv[0] = (f16)fmaxf(acc[mt][nt][0] + bv[nt].x, 0.f);
            hv[1] = (f16)fmaxf(acc[mt][nt][1] + bv[nt].y, 0.f);
            hv[2] = (f16)fmaxf(acc[mt][nt][2] + bv[nt].z, 0.f);
            hv[3] = (f16)fmaxf(acc[mt][nt][3] + bv[nt].w, 0.f);
            *(f16x4*)&tile[(mt * 16 + fr) * LDS_K + w * 32 + nt * 16 + fg * 4] = hv;
        }

    // reload fragments with W2/b2 (L2-hot), reuse registers
#pragma unroll
    for (int nt = 0; nt < 2; nt++) {
        int col = w * 32 + nt * 16 + fr;
#pragma unroll
        for (int ks = 0; ks < 4; ks++)
            wf[nt][ks] = *(const f16x8*)&W2t[col * DIM + ks * 32 + fg * 8];
        bv[nt] = *(const float4*)&b2[w * 32 + nt * 16 + fg * 4];
    }
    __syncthreads();   // H fully written

    // ---- GEMM2 (swapped): lane holds OUT[n][m], store 8B direct to global
#pragma unroll
    for (int mt = 0; mt < 4; mt++)
#pragma unroll
        for (int nt = 0; nt < 2; nt++) acc[mt][nt] = (f32x4){0.f, 0.f, 0.f, 0.f};

#pragma unroll
    for (int mt = 0; mt < 4; mt++)
#pragma unroll
        for (int ks = 0; ks < 4; ks++) {
            f16x8 a = *(const f16x8*)&tile[(mt * 16 + fr) * LDS_K + ks * 32 + fg * 8];
            acc[mt][0] = MFMA16(wf[0][ks], a, acc[mt][0]);
            acc[mt][1] = MFMA16(wf[1][ks], a, acc[mt][1]);
        }

#pragma unroll
    for (int mt = 0; mt < 4; mt++)
#pragma unroll
        for (int nt = 0; nt < 2; nt++) {
            f16x4 ov;
            ov[0] = (f16)fmaxf(acc[mt][nt][0] + bv[nt].x, 0.f);
            ov[1] = (f16)fmaxf(acc[mt][nt][1] + bv[nt].y, 0.f);
            ov[2] = (f16)fmaxf(acc[mt][nt][2] + bv[nt].z, 0.f);
            ov[3] = (f16)fmaxf(acc[mt][nt][3] + bv[nt].w, 0.f);
            *(f16x4*)&xout[(size_t)(row0 + mt * 16 + fr) * DIM + w * 32 + nt * 16 + fg * 4] = ov;
        }
}

// ---------------- pool ----------------

__global__ void k_pool(const f16* __restrict__ xf, const int* __restrict__ batch,
                       float* __restrict__ out) {
    int g = blockIdx.x;
    int d = threadIdx.x;
    int lo = 0, hi = N_NODES;
    while (lo < hi) { int m = (lo + hi) >> 1; if (batch[m] < g) lo = m + 1; else hi = m; }
    int start = lo;
    hi = N_NODES;
    while (lo < hi) { int m = (lo + hi) >> 1; if (batch[m] <= g) lo = m + 1; else hi = m; }
    int end = lo;
    float acc = 0.f;
    for (int i = start; i < end; i++) acc += (float)xf[(size_t)i * DIM + d];
    float cntf = (float)(end - start);
    out[(size_t)g * DIM + d] = acc / fmaxf(cntf, 1.f);
}

// ---------------- launch ----------------

extern "C" void kernel_launch(void* const* d_in, const int* in_sizes, int n_in,
                              void* d_out, int out_size, void* d_ws, size_t ws_size,
                              hipStream_t stream) {
    const float* x     = (const float*)d_in[0];
    const int*   ei    = (const int*)d_in[1];
    const int*   batch = (const int*)d_in[2];
    const float* W1    = (const float*)d_in[3];
    const float* b1    = (const float*)d_in[4];
    const float* W2    = (const float*)d_in[5];
    const float* b2    = (const float*)d_in[6];
    const int* src = ei;
    const int* dst = ei + N_EDGES;

    char* ws = (char*)d_ws;
    int*      offs  = (int*)(ws + OFF_OFFS);
    int*      btot  = (int*)(ws + OFF_BHT);
    int*      bst   = (int*)(ws + OFF_BST);
    int*      gcur  = (int*)(ws + OFF_GCUR);
    int*      blkh  = (int*)(ws + OFF_BLKH);
    int*      esrc  = (int*)(ws + OFF_ESRC);
    uint32_t* pairs = (uint32_t*)(ws + OFF_PAIR);
    f16*      x16   = (f16*)(ws + OFF_X16);
    f16*      a16   = (f16*)(ws + OFF_A16);
    f16*      b16   = (f16*)(ws + OFF_B16);
    f16*      w1t   = (f16*)(ws + OFF_W1T);
    f16*      w2t   = (f16*)(ws + OFF_W2T);
    float*    outp  = (float*)d_out;

    // CSR build via bucket partition
    hipMemsetAsync(btot, 0, NBUCKET * sizeof(int), stream);
    k_bhist<<<P1GRID, 256, 0, stream>>>(dst, btot, blkh);
    k_bscan<<<1, 256, 0, stream>>>(btot, bst, gcur, offs);
    k_part1<<<P1GRID, 256, 0, stream>>>(src, dst, blkh, gcur, pairs);
    k_part2<<<NBUCKET, 256, 0, stream>>>(pairs, bst, offs, esrc);

    // conversions
    k_cvtX<<<6250, 256, 0, stream>>>(x, x16);
    k_cvtW<<<192, 256, 0, stream>>>(W1, w1t);
    k_cvtW<<<192, 256, 0, stream>>>(W2, w2t);

    // 3 fused GIN layers (gather+MLP)
    const f16* xin = x16;
    for (int l = 0; l < N_LAYERS; ++l) {
        f16* xoutb = (l == 1) ? b16 : a16;   // x16 -> A -> B -> A
        k_fused<<<N_PAD / BM, 256, 0, stream>>>(xin, xoutb, offs, esrc,
                                                w1t + (size_t)l * DIM * DIM, b1 + (size_t)l * DIM,
                                                w2t + (size_t)l * DIM * DIM, b2 + (size_t)l * DIM);
        xin = xoutb;
    }

    k_pool<<<N_GRAPHS, 128, 0, stream>>>(xin, batch, outp);
}

// Round 6
// 361.080 us; speedup vs baseline: 1.2599x; 1.2599x over previous
//
#include <hip/hip_runtime.h>
#include <hip/hip_bf16.h>
#include <stdint.h>

#define N_NODES  100000
#define N_PAD    100032          // padded to multiple of 64 for MLP tiles
#define N_EDGES  1600000
#define DIM      128
#define N_LAYERS 3
#define N_GRAPHS 2048

#define BSHIFT   8               // bucket = 256 consecutive dst nodes
#define NBUCKET  391             // ceil(N_NODES / 256)
#define P1CHUNK  4096
#define P1GRID   391             // ceil(N_EDGES / P1CHUNK)

typedef _Float16 f16;
typedef __attribute__((ext_vector_type(2))) _Float16 f16x2;
typedef __attribute__((ext_vector_type(4))) _Float16 f16x4;
typedef __attribute__((ext_vector_type(8))) _Float16 f16x8;
typedef __attribute__((ext_vector_type(4))) float f32x4;
typedef __attribute__((ext_vector_type(4))) int i32x4;

#define MFMA16(a, b, c) __builtin_amdgcn_mfma_f32_16x16x32_f16((a), (b), (c), 0, 0, 0)

// ---------------- workspace layout (bytes, 64B-aligned) ----------------
#define OFF_OFFS  0u             // (N_NODES+1) ints
#define OFF_BHT   400064u        // NBUCKET ints (bucket totals)
#define OFF_BST   401664u        // NBUCKET+1 ints (bucket starts)
#define OFF_GCUR  403264u        // NBUCKET ints (bucket cursors)
#define OFF_BLKH  404864u        // P1GRID*NBUCKET ints (per-block bucket hist)
#define OFF_ESRC  1016448u       // N_EDGES ints
#define OFF_PAIR  7416448u       // N_EDGES u32 packed (src<<8 | d&255)
#define OFF_X16   13816448u      // N_PAD*DIM f16
#define OFF_A16   39424640u      // N_PAD*DIM f16
#define OFF_B16   65032832u      // N_PAD*DIM f16
#define OFF_W1T   90641024u      // 3*128*128 f16 ([l][n][k])
#define OFF_W2T   90739328u      // 3*128*128 f16
// end ~90.8 MB

// ---------------- CSR build: bucket partition ----------------

__global__ __launch_bounds__(256) void k_bhist(const int* __restrict__ dst,
                                               int* __restrict__ btot, int* __restrict__ blkh) {
    __shared__ int h[NBUCKET];
    int tid = threadIdx.x, b = blockIdx.x;
    for (int i = tid; i < NBUCKET; i += 256) h[i] = 0;
    __syncthreads();
    int base = b * P1CHUNK;
    int n = min(P1CHUNK, N_EDGES - base);
    for (int i = tid; i < n; i += 256)
        atomicAdd(&h[dst[base + i] >> BSHIFT], 1);
    __syncthreads();
    for (int i = tid; i < NBUCKET; i += 256) {
        blkh[b * NBUCKET + i] = h[i];
        atomicAdd(&btot[i], h[i]);
    }
}

__global__ void k_bscan(const int* __restrict__ btot, int* __restrict__ bstart,
                        int* __restrict__ gcursor, int* __restrict__ offs) {
    __shared__ int s[NBUCKET + 1];
    if (threadIdx.x == 0) {
        int run = 0;
        for (int i = 0; i < NBUCKET; i++) { s[i] = run; run += btot[i]; }
        s[NBUCKET] = run;
    }
    __syncthreads();
    int t = threadIdx.x;
    for (int i = t; i <= NBUCKET; i += 256) bstart[i] = s[i];
    for (int i = t; i < NBUCKET; i += 256)  gcursor[i] = s[i];
    if (t == 0) offs[N_NODES] = N_EDGES;
}

__global__ __launch_bounds__(256) void k_part1(const int* __restrict__ src, const int* __restrict__ dst,
                                               const int* __restrict__ blkh, int* __restrict__ gcursor,
                                               uint32_t* __restrict__ pairs) {
    __shared__ int gbase[NBUCKET];
    __shared__ int cur[NBUCKET];
    int tid = threadIdx.x, b = blockIdx.x;
    for (int i = tid; i < NBUCKET; i += 256) {
        int h = blkh[b * NBUCKET + i];
        gbase[i] = atomicAdd(&gcursor[i], h);
        cur[i] = 0;
    }
    __syncthreads();
    int base = b * P1CHUNK;
    int n = min(P1CHUNK, N_EDGES - base);
    for (int i = tid; i < n; i += 256) {
        int d = dst[base + i], s = src[base + i];
        int bin = d >> BSHIFT;
        int slot = atomicAdd(&cur[bin], 1);
        pairs[gbase[bin] + slot] = ((uint32_t)s << 8) | (uint32_t)(d & 255);
    }
}

__global__ __launch_bounds__(256) void k_part2(const uint32_t* __restrict__ pairs,
                                               const int* __restrict__ bstart,
                                               int* __restrict__ offs, int* __restrict__ esrc) {
    __shared__ int cnt[256];
    __shared__ int cur[256];
    __shared__ int sc[256];
    int t = threadIdx.x, b = blockIdx.x;
    int n0 = b << BSHIFT;
    int nn = min(256, N_NODES - n0);
    int e0 = bstart[b], e1 = bstart[b + 1];
    cnt[t] = 0;
    __syncthreads();
    for (int i = e0 + t; i < e1; i += 256)
        atomicAdd(&cnt[pairs[i] & 255], 1);
    __syncthreads();
    int my = cnt[t];
    sc[t] = my;
    __syncthreads();
    for (int off = 1; off < 256; off <<= 1) {
        int v = (t >= off) ? sc[t - off] : 0;
        __syncthreads();
        sc[t] += v;
        __syncthreads();
    }
    int excl = sc[t] - my;
    cur[t] = excl;
    if (t < nn) offs[n0 + t] = e0 + excl;
    __syncthreads();
    for (int i = e0 + t; i < e1; i += 256) {
        uint32_t p = pairs[i];
        int pos = e0 + atomicAdd(&cur[p & 255], 1);
        esrc[pos] = (int)(p >> 8);          // 16KB region, single block -> single XCD
    }
}

// ---------------- dtype conversion ----------------

__global__ void k_cvtX(const float* __restrict__ x, f16* __restrict__ o) {
    size_t i = ((size_t)blockIdx.x * 256 + threadIdx.x) * 8;
    float4 v0 = *(const float4*)&x[i];
    float4 v1 = *(const float4*)&x[i + 4];
    f16x8 h;
    h[0] = (f16)v0.x; h[1] = (f16)v0.y; h[2] = (f16)v0.z; h[3] = (f16)v0.w;
    h[4] = (f16)v1.x; h[5] = (f16)v1.y; h[6] = (f16)v1.z; h[7] = (f16)v1.w;
    *(f16x8*)&o[i] = h;
}

// W: [3][k][n] f32 -> Wt: [3][n][k] f16
__global__ void k_cvtW(const float* __restrict__ W, f16* __restrict__ Wt) {
    int t = blockIdx.x * 256 + threadIdx.x;
    int l = t >> 14;
    int kn = t & 16383;
    int k = kn >> 7, n = kn & 127;
    Wt[l * 16384 + n * 128 + k] = (f16)W[t];
}

// ---------------- aggregation: out[i] = x[i] + sum_{j in N(i)} x[j] ----------------
// wave per node; 4 edge-groups x 16 cols; 4-deep unconditional unroll + one
// masked remainder round; packed-f16 accumulation (v_pk_add_f16).

__global__ __launch_bounds__(256) void k_agg(const f16* __restrict__ x, const int* __restrict__ offs,
                                             const int* __restrict__ esrc, f16* __restrict__ out) {
    int tid  = threadIdx.x;
    int node = blockIdx.x * 4 + (tid >> 6);     // grid is exactly N_NODES/4
    int lane = tid & 63;
    int g    = lane >> 4;                       // edge group 0..3
    int c    = lane & 15;                       // 16B column (dims c*8..c*8+7)
    const f16x8* xr = (const f16x8*)x;          // 16 chunks per row

    int e0 = offs[node], e1 = offs[node + 1];

    f16x8 sum = {(f16)0, (f16)0, (f16)0, (f16)0, (f16)0, (f16)0, (f16)0, (f16)0};
    f16x8 sv = xr[(size_t)node * 16 + c];
    if (g == 0) sum = sv;                       // self term counted once

    int e = e0 + g;
    // main: 16 edges per wave-round, 4 loads in flight per lane-group
    for (; e + 12 < e1; e += 16) {
        int s0 = esrc[e], s1 = esrc[e + 4], s2 = esrc[e + 8], s3 = esrc[e + 12];
        f16x8 v0 = xr[(size_t)s0 * 16 + c];
        f16x8 v1 = xr[(size_t)s1 * 16 + c];
        f16x8 v2 = xr[(size_t)s2 * 16 + c];
        f16x8 v3 = xr[(size_t)s3 * 16 + c];
        sum += v0; sum += v1; sum += v2; sum += v3;
    }
    // remainder: one masked round (loads unconditional via clamped index)
    if (e < e1) {
        int i1 = e + 4, i2 = e + 8, i3 = e + 12;
        bool k1 = i1 < e1, k2 = i2 < e1, k3 = i3 < e1;
        int s0 = esrc[e];
        int s1 = esrc[k1 ? i1 : e0];
        int s2 = esrc[k2 ? i2 : e0];
        int s3 = esrc[k3 ? i3 : e0];
        f16x8 v0 = xr[(size_t)s0 * 16 + c];
        f16x8 v1 = xr[(size_t)s1 * 16 + c];
        f16x8 v2 = xr[(size_t)s2 * 16 + c];
        f16x8 v3 = xr[(size_t)s3 * 16 + c];
        sum += v0;
        if (k1) sum += v1;
        if (k2) sum += v2;
        if (k3) sum += v3;
    }

    // combine the 4 edge groups (packed shuffles)
    {
        i32x4 a = __builtin_bit_cast(i32x4, sum), b;
        b.x = __shfl_xor(a.x, 16); b.y = __shfl_xor(a.y, 16);
        b.z = __shfl_xor(a.z, 16); b.w = __shfl_xor(a.w, 16);
        sum += __builtin_bit_cast(f16x8, b);
        a = __builtin_bit_cast(i32x4, sum);
        b.x = __shfl_xor(a.x, 32); b.y = __shfl_xor(a.y, 32);
        b.z = __shfl_xor(a.z, 32); b.w = __shfl_xor(a.w, 32);
        sum += __builtin_bit_cast(f16x8, b);
    }
    if (g == 0)
        ((f16x8*)out)[(size_t)node * 16 + c] = sum;
}

// ---------------- MLP: out = relu(relu(in@W1+b1)@W2+b2), swapped-operand MFMA ----------------

#define BM 64
#define LDS_K 136    // padded row stride in f16 (272 B)

__global__ __launch_bounds__(256) void k_mlp(
    const f16* __restrict__ in, f16* __restrict__ xout,
    const f16* __restrict__ W1t, const float* __restrict__ b1,
    const f16* __restrict__ W2t, const float* __restrict__ b2)
{
    __shared__ __align__(16) f16 tile[BM * LDS_K];
    int tid  = threadIdx.x;
    int lane = tid & 63;
    int w    = tid >> 6;          // wave 0..3
    int fr   = lane & 15;
    int fg   = lane >> 4;
    int row0 = blockIdx.x * BM;

    // stage input tile: 64 rows x 256 B, coalesced
#pragma unroll
    for (int p = 0; p < 4; p++) {
        int idx = p * 256 + tid;
        int r = idx >> 4, c = idx & 15;
        *(float4*)&tile[r * LDS_K + c * 8] = *(const float4*)&in[(size_t)(row0 + r) * DIM + c * 8];
    }

    // W1 fragments + bias (overlap with staging; independent of LDS)
    f16x8 wf[2][4];
    float4 bv[2];
#pragma unroll
    for (int nt = 0; nt < 2; nt++) {
        int col = w * 32 + nt * 16 + fr;
#pragma unroll
        for (int ks = 0; ks < 4; ks++)
            wf[nt][ks] = *(const f16x8*)&W1t[col * DIM + ks * 32 + fg * 8];
        bv[nt] = *(const float4*)&b1[w * 32 + nt * 16 + fg * 4];
    }
    __syncthreads();

    // GEMM1 (swapped operands): lane holds H[m=mt*16+fr][n=w*32+nt*16+fg*4+r]
    f32x4 acc[4][2];
#pragma unroll
    for (int mt = 0; mt < 4; mt++)
#pragma unroll
        for (int nt = 0; nt < 2; nt++) acc[mt][nt] = (f32x4){0.f, 0.f, 0.f, 0.f};

#pragma unroll
    for (int mt = 0; mt < 4; mt++)
#pragma unroll
        for (int ks = 0; ks < 4; ks++) {
            f16x8 a = *(const f16x8*)&tile[(mt * 16 + fr) * LDS_K + ks * 32 + fg * 8];
            acc[mt][0] = MFMA16(wf[0][ks], a, acc[mt][0]);
            acc[mt][1] = MFMA16(wf[1][ks], a, acc[mt][1]);
        }
    __syncthreads();   // all X reads done before overwriting tile with H

    // H epilogue: relu(acc+b1) -> tile[node][feature], 8B vector writes
#pragma unroll
    for (int mt = 0; mt < 4; mt++)
#pragma unroll
        for (int nt = 0; nt < 2; nt++) {
            f16x4 hv;
            hv[0] = (f16)fmaxf(acc[mt][nt][0] + bv[nt].x, 0.f);
            hv[1] = (f16)fmaxf(acc[mt][nt][1] + bv[nt].y, 0.f);
            hv[2] = (f16)fmaxf(acc[mt][nt][2] + bv[nt].z, 0.f);
            hv[3] = (f16)fmaxf(acc[mt][nt][3] + bv[nt].w, 0.f);
            *(f16x4*)&tile[(mt * 16 + fr) * LDS_K + w * 32 + nt * 16 + fg * 4] = hv;
        }

    // reload fragments with W2/b2 (L2-hot), reuse registers
#pragma unroll
    for (int nt = 0; nt < 2; nt++) {
        int col = w * 32 + nt * 16 + fr;
#pragma unroll
        for (int ks = 0; ks < 4; ks++)
            wf[nt][ks] = *(const f16x8*)&W2t[col * DIM + ks * 32 + fg * 8];
        bv[nt] = *(const float4*)&b2[w * 32 + nt * 16 + fg * 4];
    }
    __syncthreads();   // H fully written

    // GEMM2 (swapped): store direct to global, 8B per lane
#pragma unroll
    for (int mt = 0; mt < 4; mt++)
#pragma unroll
        for (int nt = 0; nt < 2; nt++) acc[mt][nt] = (f32x4){0.f, 0.f, 0.f, 0.f};

#pragma unroll
    for (int mt = 0; mt < 4; mt++)
#pragma unroll
        for (int ks = 0; ks < 4; ks++) {
            f16x8 a = *(const f16x8*)&tile[(mt * 16 + fr) * LDS_K + ks * 32 + fg * 8];
            acc[mt][0] = MFMA16(wf[0][ks], a, acc[mt][0]);
            acc[mt][1] = MFMA16(wf[1][ks], a, acc[mt][1]);
        }

#pragma unroll
    for (int mt = 0; mt < 4; mt++)
#pragma unroll
        for (int nt = 0; nt < 2; nt++) {
            f16x4 ov;
            ov[0] = (f16)fmaxf(acc[mt][nt][0] + bv[nt].x, 0.f);
            ov[1] = (f16)fmaxf(acc[mt][nt][1] + bv[nt].y, 0.f);
            ov[2] = (f16)fmaxf(acc[mt][nt][2] + bv[nt].z, 0.f);
            ov[3] = (f16)fmaxf(acc[mt][nt][3] + bv[nt].w, 0.f);
            *(f16x4*)&xout[(size_t)(row0 + mt * 16 + fr) * DIM + w * 32 + nt * 16 + fg * 4] = ov;
        }
}

// ---------------- pool ----------------

__global__ void k_pool(const f16* __restrict__ xf, const int* __restrict__ batch,
                       float* __restrict__ out) {
    int g = blockIdx.x;
    int d = threadIdx.x;
    int lo = 0, hi = N_NODES;
    while (lo < hi) { int m = (lo + hi) >> 1; if (batch[m] < g) lo = m + 1; else hi = m; }
    int start = lo;
    hi = N_NODES;
    while (lo < hi) { int m = (lo + hi) >> 1; if (batch[m] <= g) lo = m + 1; else hi = m; }
    int end = lo;
    float acc = 0.f;
    for (int i = start; i < end; i++) acc += (float)xf[(size_t)i * DIM + d];
    float cntf = (float)(end - start);
    out[(size_t)g * DIM + d] = acc / fmaxf(cntf, 1.f);
}

// ---------------- launch ----------------

extern "C" void kernel_launch(void* const* d_in, const int* in_sizes, int n_in,
                              void* d_out, int out_size, void* d_ws, size_t ws_size,
                              hipStream_t stream) {
    const float* x     = (const float*)d_in[0];
    const int*   ei    = (const int*)d_in[1];
    const int*   batch = (const int*)d_in[2];
    const float* W1    = (const float*)d_in[3];
    const float* b1    = (const float*)d_in[4];
    const float* W2    = (const float*)d_in[5];
    const float* b2    = (const float*)d_in[6];
    const int* src = ei;
    const int* dst = ei + N_EDGES;

    char* ws = (char*)d_ws;
    int*      offs  = (int*)(ws + OFF_OFFS);
    int*      btot  = (int*)(ws + OFF_BHT);
    int*      bst   = (int*)(ws + OFF_BST);
    int*      gcur  = (int*)(ws + OFF_GCUR);
    int*      blkh  = (int*)(ws + OFF_BLKH);
    int*      esrc  = (int*)(ws + OFF_ESRC);
    uint32_t* pairs = (uint32_t*)(ws + OFF_PAIR);
    f16*      x16   = (f16*)(ws + OFF_X16);
    f16*      a16   = (f16*)(ws + OFF_A16);
    f16*      b16   = (f16*)(ws + OFF_B16);
    f16*      w1t   = (f16*)(ws + OFF_W1T);
    f16*      w2t   = (f16*)(ws + OFF_W2T);
    float*    outp  = (float*)d_out;

    // CSR build via bucket partition
    hipMemsetAsync(btot, 0, NBUCKET * sizeof(int), stream);
    k_bhist<<<P1GRID, 256, 0, stream>>>(dst, btot, blkh);
    k_bscan<<<1, 256, 0, stream>>>(btot, bst, gcur, offs);
    k_part1<<<P1GRID, 256, 0, stream>>>(src, dst, blkh, gcur, pairs);
    k_part2<<<NBUCKET, 256, 0, stream>>>(pairs, bst, offs, esrc);

    // conversions
    k_cvtX<<<6250, 256, 0, stream>>>(x, x16);
    k_cvtW<<<192, 256, 0, stream>>>(W1, w1t);
    k_cvtW<<<192, 256, 0, stream>>>(W2, w2t);

    // 3 GIN layers (split agg / MLP)
    const f16* xin = x16;
    for (int l = 0; l < N_LAYERS; ++l) {
        f16* buf = (l == 1) ? b16 : a16;   // x16 -> A -> B -> A
        k_agg<<<N_NODES / 4, 256, 0, stream>>>(xin, offs, esrc, buf);
        k_mlp<<<N_PAD / BM, 256, 0, stream>>>(buf, buf,
                                              w1t + (size_t)l * DIM * DIM, b1 + (size_t)l * DIM,
                                              w2t + (size_t)l * DIM * DIM, b2 + (size_t)l * DIM);
        xin = buf;
    }

    k_pool<<<N_GRAPHS, 128, 0, stream>>>(xin, batch, outp);
}

// Round 8
// 322.049 us; speedup vs baseline: 1.4126x; 1.1212x over previous
//
#include <hip/hip_runtime.h>
#include <hip/hip_bf16.h>
#include <stdint.h>

#define N_NODES  100000
#define N_PAD    100032          // padded to multiple of 64 for MLP tiles
#define N_EDGES  1600000
#define DIM      128
#define N_LAYERS 3
#define N_GRAPHS 2048

#define BSHIFT   8               // bucket = 256 consecutive dst nodes
#define NBUCKET  391             // ceil(N_NODES / 256)
#define P1CHUNK  4096
#define P1GRID   391             // ceil(N_EDGES / P1CHUNK)

typedef _Float16 f16;
typedef __attribute__((ext_vector_type(4))) _Float16 f16x4;
typedef __attribute__((ext_vector_type(8))) _Float16 f16x8;
typedef __attribute__((ext_vector_type(4))) float f32x4;

#define MFMA16(a, b, c) __builtin_amdgcn_mfma_f32_16x16x32_f16((a), (b), (c), 0, 0, 0)

// ---------------- workspace layout (bytes, 64B-aligned) ----------------
#define OFF_OFFS  0u             // (N_NODES+1) ints
#define OFF_BHT   400064u        // NBUCKET ints (bucket totals)
#define OFF_BST   401664u        // NBUCKET+1 ints (bucket starts)
#define OFF_GCUR  403264u        // NBUCKET ints (bucket cursors)
#define OFF_BLKH  404864u        // P1GRID*NBUCKET ints (per-block bucket hist)
#define OFF_ESRC  1016448u       // N_EDGES ints
#define OFF_PAIR  7416448u       // N_EDGES u32 packed (src<<8 | d&255)
#define OFF_X16   13816448u      // N_PAD*DIM f16
#define OFF_A16   39424640u      // N_PAD*DIM f16
#define OFF_B16   65032832u      // N_PAD*DIM f16
#define OFF_W1T   90641024u      // 3*128*128 f16 ([l][n][k])
#define OFF_W2T   90739328u      // 3*128*128 f16
// end ~90.8 MB

// ---------------- CSR build: bucket partition (4 kernels, proven) ----------------

__global__ __launch_bounds__(256) void k_bhist(const int* __restrict__ dst,
                                               int* __restrict__ btot, int* __restrict__ blkh) {
    __shared__ int h[NBUCKET];
    int tid = threadIdx.x, b = blockIdx.x;
    for (int i = tid; i < NBUCKET; i += 256) h[i] = 0;
    __syncthreads();
    int base = b * P1CHUNK;
    int n = min(P1CHUNK, N_EDGES - base);
    for (int i = tid; i < n; i += 256)
        atomicAdd(&h[dst[base + i] >> BSHIFT], 1);
    __syncthreads();
    for (int i = tid; i < NBUCKET; i += 256) {
        blkh[b * NBUCKET + i] = h[i];
        atomicAdd(&btot[i], h[i]);
    }
}

// 1-block parallel exclusive scan of btot[NBUCKET] (padded to 512)
__global__ __launch_bounds__(256) void k_bscan(const int* __restrict__ btot,
                                               int* __restrict__ bstart,
                                               int* __restrict__ gcursor,
                                               int* __restrict__ offs) {
    __shared__ int s[512];
    int t = threadIdx.x;
    s[t]       = (t < NBUCKET) ? btot[t] : 0;
    s[t + 256] = (t + 256 < NBUCKET) ? btot[t + 256] : 0;
    __syncthreads();
    for (int off = 1; off < 512; off <<= 1) {
        int a0 = (t >= off) ? s[t - off] : 0;
        int a1 = (t + 256 >= off) ? s[t + 256 - off] : 0;
        __syncthreads();
        s[t] += a0; s[t + 256] += a1;
        __syncthreads();
    }
    int e0 = (t == 0) ? 0 : s[t - 1];     // exclusive starts
    int e1 = s[t + 255];
    if (t < NBUCKET) { bstart[t] = e0; gcursor[t] = e0; }
    int idx = t + 256;
    if (idx <= NBUCKET) { bstart[idx] = e1; if (idx < NBUCKET) gcursor[idx] = e1; }
    if (t == 0) offs[N_NODES] = N_EDGES;
}

__global__ __launch_bounds__(256) void k_part1(const int* __restrict__ src, const int* __restrict__ dst,
                                               const int* __restrict__ blkh, int* __restrict__ gcursor,
                                               uint32_t* __restrict__ pairs) {
    __shared__ int gbase[NBUCKET];
    __shared__ int cur[NBUCKET];
    int tid = threadIdx.x, b = blockIdx.x;
    for (int i = tid; i < NBUCKET; i += 256) {
        int h = blkh[b * NBUCKET + i];
        gbase[i] = atomicAdd(&gcursor[i], h);
        cur[i] = 0;
    }
    __syncthreads();
    int base = b * P1CHUNK;
    int n = min(P1CHUNK, N_EDGES - base);
    for (int i = tid; i < n; i += 256) {
        int d = dst[base + i], s = src[base + i];
        int bin = d >> BSHIFT;
        int slot = atomicAdd(&cur[bin], 1);
        pairs[gbase[bin] + slot] = ((uint32_t)s << 8) | (uint32_t)(d & 255);
    }
}

__global__ __launch_bounds__(256) void k_part2(const uint32_t* __restrict__ pairs,
                                               const int* __restrict__ bstart,
                                               int* __restrict__ offs, int* __restrict__ esrc) {
    __shared__ int cnt[256];
    __shared__ int cur[256];
    __shared__ int sc[256];
    int t = threadIdx.x, b = blockIdx.x;
    int n0 = b << BSHIFT;
    int nn = min(256, N_NODES - n0);
    int e0 = bstart[b], e1 = bstart[b + 1];
    cnt[t] = 0;
    __syncthreads();
    for (int i = e0 + t; i < e1; i += 256)
        atomicAdd(&cnt[pairs[i] & 255], 1);
    __syncthreads();
    int my = cnt[t];
    sc[t] = my;
    __syncthreads();
    for (int off = 1; off < 256; off <<= 1) {
        int v = (t >= off) ? sc[t - off] : 0;
        __syncthreads();
        sc[t] += v;
        __syncthreads();
    }
    int excl = sc[t] - my;
    cur[t] = excl;
    if (t < nn) offs[n0 + t] = e0 + excl;
    __syncthreads();
    for (int i = e0 + t; i < e1; i += 256) {
        uint32_t p = pairs[i];
        int pos = e0 + atomicAdd(&cur[p & 255], 1);
        esrc[pos] = (int)(p >> 8);          // 16KB region, single block -> single XCD
    }
}

// ---------------- dtype conversion ----------------

__global__ void k_cvtX(const float* __restrict__ x, f16* __restrict__ o) {
    size_t i = ((size_t)blockIdx.x * 256 + threadIdx.x) * 8;
    float4 v0 = *(const float4*)&x[i];
    float4 v1 = *(const float4*)&x[i + 4];
    f16x8 h;
    h[0] = (f16)v0.x; h[1] = (f16)v0.y; h[2] = (f16)v0.z; h[3] = (f16)v0.w;
    h[4] = (f16)v1.x; h[5] = (f16)v1.y; h[6] = (f16)v1.z; h[7] = (f16)v1.w;
    *(f16x8*)&o[i] = h;
}

// both weight tensors: [3][k][n] f32 -> [3][n][k] f16  (explicit subtraction!)
__global__ void k_cvtW(const float* __restrict__ W1, const float* __restrict__ W2,
                       f16* __restrict__ W1t, f16* __restrict__ W2t) {
    int t = blockIdx.x * 256 + threadIdx.x;     // 98304 total
    bool first = t < 49152;
    const float* W = first ? W1 : W2;
    f16* Wt = first ? W1t : W2t;
    int u = first ? t : t - 49152;
    int l = u >> 14;
    int kn = u & 16383;
    int k = kn >> 7, nn = kn & 127;
    Wt[l * 16384 + nn * 128 + k] = (f16)W[u];
}

// ---------------- fused layer: gather-agg -> LDS tile -> MLP -> global ----------------
// out = relu(relu((x_i + sum_j x_j) @ W1 + b1) @ W2 + b2)
// Gather: each 16-lane group owns one node (4 nodes concurrent / wave),
// 8-deep edge unroll, per-lane accumulation (no cross-lane reduce).

#define BM 64
#define LDS_K 136    // padded row stride in f16 (272 B)

__global__ __launch_bounds__(256) void k_fused(
    const f16* __restrict__ xin, f16* __restrict__ xout,
    const int* __restrict__ offs, const int* __restrict__ esrc,
    const f16* __restrict__ W1t, const float* __restrict__ b1,
    const f16* __restrict__ W2t, const float* __restrict__ b2)
{
    __shared__ __align__(16) f16 tile[BM * LDS_K];
    int tid  = threadIdx.x;
    int lane = tid & 63;
    int w    = tid >> 6;          // wave 0..3
    int fr   = lane & 15;
    int fg   = lane >> 4;
    int row0 = blockIdx.x * BM;

    // ---- gather phase
    {
        const f16x8* xr = (const f16x8*)xin;   // 16 x 16B chunks per row
        int c = fr;
#pragma unroll
        for (int t4 = 0; t4 < 4; t4++) {
            int r = w * 16 + t4 * 4 + fg;
            int node = row0 + r;
            f16x8 sum = {(f16)0, (f16)0, (f16)0, (f16)0, (f16)0, (f16)0, (f16)0, (f16)0};
            if (node < N_NODES) {
                sum = xr[(size_t)node * 16 + c];            // self term
                int e0 = offs[node], e1 = offs[node + 1];
                int e = e0;
                for (; e + 8 <= e1; e += 8) {
                    int s0 = esrc[e + 0], s1 = esrc[e + 1], s2 = esrc[e + 2], s3 = esrc[e + 3];
                    int s4 = esrc[e + 4], s5 = esrc[e + 5], s6 = esrc[e + 6], s7 = esrc[e + 7];
                    f16x8 v0 = xr[(size_t)s0 * 16 + c], v1 = xr[(size_t)s1 * 16 + c];
                    f16x8 v2 = xr[(size_t)s2 * 16 + c], v3 = xr[(size_t)s3 * 16 + c];
                    f16x8 v4 = xr[(size_t)s4 * 16 + c], v5 = xr[(size_t)s5 * 16 + c];
                    f16x8 v6 = xr[(size_t)s6 * 16 + c], v7 = xr[(size_t)s7 * 16 + c];
                    sum += (v0 + v1) + (v2 + v3);
                    sum += (v4 + v5) + (v6 + v7);
                }
                if (e < e1) {                               // masked remainder (<=7)
                    int i1 = e + 1, i2 = e + 2, i3 = e + 3, i4 = e + 4, i5 = e + 5, i6 = e + 6, i7 = e + 7;
                    bool k1 = i1 < e1, k2 = i2 < e1, k3 = i3 < e1, k4 = i4 < e1,
                         k5 = i5 < e1, k6 = i6 < e1, k7 = i7 < e1;
                    int s0 = esrc[e];
                    int s1 = esrc[k1 ? i1 : e], s2 = esrc[k2 ? i2 : e], s3 = esrc[k3 ? i3 : e];
                    int s4 = esrc[k4 ? i4 : e], s5 = esrc[k5 ? i5 : e], s6 = esrc[k6 ? i6 : e];
                    int s7 = esrc[k7 ? i7 : e];
                    f16x8 v0 = xr[(size_t)s0 * 16 + c], v1 = xr[(size_t)s1 * 16 + c];
                    f16x8 v2 = xr[(size_t)s2 * 16 + c], v3 = xr[(size_t)s3 * 16 + c];
                    f16x8 v4 = xr[(size_t)s4 * 16 + c], v5 = xr[(size_t)s5 * 16 + c];
                    f16x8 v6 = xr[(size_t)s6 * 16 + c], v7 = xr[(size_t)s7 * 16 + c];
                    sum += v0;
                    if (k1) sum += v1;
                    if (k2) sum += v2;
                    if (k3) sum += v3;
                    if (k4) sum += v4;
                    if (k5) sum += v5;
                    if (k6) sum += v6;
                    if (k7) sum += v7;
                }
            }
            *(f16x8*)&tile[r * LDS_K + c * 8] = sum;        // full row, no masking
        }
    }

    // W1 fragments + bias (issued before the barrier to overlap)
    f16x8 wf[2][4];
    float4 bv[2];
#pragma unroll
    for (int nt = 0; nt < 2; nt++) {
        int col = w * 32 + nt * 16 + fr;
#pragma unroll
        for (int ks = 0; ks < 4; ks++)
            wf[nt][ks] = *(const f16x8*)&W1t[col * DIM + ks * 32 + fg * 8];
        bv[nt] = *(const float4*)&b1[w * 32 + nt * 16 + fg * 4];
    }
    __syncthreads();

    // ---- GEMM1 (swapped operands): lane holds H[m=mt*16+fr][n=w*32+nt*16+fg*4+r]
    f32x4 acc[4][2];
#pragma unroll
    for (int mt = 0; mt < 4; mt++)
#pragma unroll
        for (int nt = 0; nt < 2; nt++) acc[mt][nt] = (f32x4){0.f, 0.f, 0.f, 0.f};

#pragma unroll
    for (int mt = 0; mt < 4; mt++)
#pragma unroll
        for (int ks = 0; ks < 4; ks++) {
            f16x8 a = *(const f16x8*)&tile[(mt * 16 + fr) * LDS_K + ks * 32 + fg * 8];
            acc[mt][0] = MFMA16(wf[0][ks], a, acc[mt][0]);
            acc[mt][1] = MFMA16(wf[1][ks], a, acc[mt][1]);
        }
    __syncthreads();   // all X reads done before overwriting tile with H

    // H epilogue: relu(acc+b1) -> tile[node][feature], 8B vector writes
#pragma unroll
    for (int mt = 0; mt < 4; mt++)
#pragma unroll
        for (int nt = 0; nt < 2; nt++) {
            f16x4 hv;
            hv[0] = (f16)fmaxf(acc[mt][nt][0] + bv[nt].x, 0.f);
            hv[1] = (f16)fmaxf(acc[mt][nt][1] + bv[nt].y, 0.f);
            hv[2] = (f16)fmaxf(acc[mt][nt][2] + bv[nt].z, 0.f);
            hv[3] = (f16)fmaxf(acc[mt][nt][3] + bv[nt].w, 0.f);
            *(f16x4*)&tile[(mt * 16 + fr) * LDS_K + w * 32 + nt * 16 + fg * 4] = hv;
        }

    // reload fragments with W2/b2 (L2-hot), reuse registers
#pragma unroll
    for (int nt = 0; nt < 2; nt++) {
        int col = w * 32 + nt * 16 + fr;
#pragma unroll
        for (int ks = 0; ks < 4; ks++)
            wf[nt][ks] = *(const f16x8*)&W2t[col * DIM + ks * 32 + fg * 8];
        bv[nt] = *(const float4*)&b2[w * 32 + nt * 16 + fg * 4];
    }
    __syncthreads();   // H fully written

    // ---- GEMM2 (swapped): store direct to global, 8B per lane
#pragma unroll
    for (int mt = 0; mt < 4; mt++)
#pragma unroll
        for (int nt = 0; nt < 2; nt++) acc[mt][nt] = (f32x4){0.f, 0.f, 0.f, 0.f};

#pragma unroll
    for (int mt = 0; mt < 4; mt++)
#pragma unroll
        for (int ks = 0; ks < 4; ks++) {
            f16x8 a = *(const f16x8*)&tile[(mt * 16 + fr) * LDS_K + ks * 32 + fg * 8];
            acc[mt][0] = MFMA16(wf[0][ks], a, acc[mt][0]);
            acc[mt][1] = MFMA16(wf[1][ks], a, acc[mt][1]);
        }

#pragma unroll
    for (int mt = 0; mt < 4; mt++)
#pragma unroll
        for (int nt = 0; nt < 2; nt++) {
            f16x4 ov;
            ov[0] = (f16)fmaxf(acc[mt][nt][0] + bv[nt].x, 0.f);
            ov[1] = (f16)fmaxf(acc[mt][nt][1] + bv[nt].y, 0.f);
            ov[2] = (f16)fmaxf(acc[mt][nt][2] + bv[nt].z, 0.f);
            ov[3] = (f16)fmaxf(acc[mt][nt][3] + bv[nt].w, 0.f);
            *(f16x4*)&xout[(size_t)(row0 + mt * 16 + fr) * DIM + w * 32 + nt * 16 + fg * 4] = ov;
        }
}

// ---------------- pool ----------------

__global__ void k_pool(const f16* __restrict__ xf, const int* __restrict__ batch,
                       float* __restrict__ out) {
    int g = blockIdx.x;
    int d = threadIdx.x;
    int lo = 0, hi = N_NODES;
    while (lo < hi) { int m = (lo + hi) >> 1; if (batch[m] < g) lo = m + 1; else hi = m; }
    int start = lo;
    hi = N_NODES;
    while (lo < hi) { int m = (lo + hi) >> 1; if (batch[m] <= g) lo = m + 1; else hi = m; }
    int end = lo;
    float acc = 0.f;
    for (int i = start; i < end; i++) acc += (float)xf[(size_t)i * DIM + d];
    float cntf = (float)(end - start);
    out[(size_t)g * DIM + d] = acc / fmaxf(cntf, 1.f);
}

// ---------------- launch ----------------

extern "C" void kernel_launch(void* const* d_in, const int* in_sizes, int n_in,
                              void* d_out, int out_size, void* d_ws, size_t ws_size,
                              hipStream_t stream) {
    const float* x     = (const float*)d_in[0];
    const int*   ei    = (const int*)d_in[1];
    const int*   batch = (const int*)d_in[2];
    const float* W1    = (const float*)d_in[3];
    const float* b1    = (const float*)d_in[4];
    const float* W2    = (const float*)d_in[5];
    const float* b2    = (const float*)d_in[6];
    const int* srcp = ei;
    const int* dstp = ei + N_EDGES;

    char* ws = (char*)d_ws;
    int*      offs  = (int*)(ws + OFF_OFFS);
    int*      btot  = (int*)(ws + OFF_BHT);
    int*      bst   = (int*)(ws + OFF_BST);
    int*      gcur  = (int*)(ws + OFF_GCUR);
    int*      blkh  = (int*)(ws + OFF_BLKH);
    int*      esrc  = (int*)(ws + OFF_ESRC);
    uint32_t* pairs = (uint32_t*)(ws + OFF_PAIR);
    f16*      x16   = (f16*)(ws + OFF_X16);
    f16*      a16   = (f16*)(ws + OFF_A16);
    f16*      b16   = (f16*)(ws + OFF_B16);
    f16*      w1t   = (f16*)(ws + OFF_W1T);
    f16*      w2t   = (f16*)(ws + OFF_W2T);
    float*    outp  = (float*)d_out;

    // CSR build via bucket partition
    hipMemsetAsync(btot, 0, NBUCKET * sizeof(int), stream);
    k_bhist<<<P1GRID, 256, 0, stream>>>(dstp, btot, blkh);
    k_bscan<<<1, 256, 0, stream>>>(btot, bst, gcur, offs);
    k_part1<<<P1GRID, 256, 0, stream>>>(srcp, dstp, blkh, gcur, pairs);
    k_part2<<<NBUCKET, 256, 0, stream>>>(pairs, bst, offs, esrc);

    // conversions
    k_cvtX<<<6250, 256, 0, stream>>>(x, x16);
    k_cvtW<<<384, 256, 0, stream>>>(W1, W2, w1t, w2t);

    // 3 fused GIN layers (gather + MLP)
    const f16* xin = x16;
    for (int l = 0; l < N_LAYERS; ++l) {
        f16* xoutb = (l == 1) ? b16 : a16;   // x16 -> A -> B -> A
        k_fused<<<N_PAD / BM, 256, 0, stream>>>(xin, xoutb, offs, esrc,
                                                w1t + (size_t)l * DIM * DIM, b1 + (size_t)l * DIM,
                                                w2t + (size_t)l * DIM * DIM, b2 + (size_t)l * DIM);
        xin = xoutb;
    }

    k_pool<<<N_GRAPHS, 128, 0, stream>>>(xin, batch, outp);
}

// Round 9
// 291.407 us; speedup vs baseline: 1.5611x; 1.1051x over previous
//
#include <hip/hip_runtime.h>
#include <hip/hip_bf16.h>
#include <stdint.h>

#define N_NODES  100000
#define N_PAD    100032          // padded to multiple of 64 for MLP tiles
#define N_EDGES  1600000
#define DIM      128
#define N_LAYERS 3
#define N_GRAPHS 2048

#define BSHIFT   8               // bucket = 256 consecutive dst nodes
#define NBUCKET  391             // ceil(N_NODES / 256)
#define P1CHUNK  4096
#define P1GRID   391             // ceil(N_EDGES / P1CHUNK)

typedef _Float16 f16;
typedef __attribute__((ext_vector_type(4))) _Float16 f16x4;
typedef __attribute__((ext_vector_type(8))) _Float16 f16x8;
typedef __attribute__((ext_vector_type(4))) float f32x4;

#define MFMA16(a, b, c) __builtin_amdgcn_mfma_f32_16x16x32_f16((a), (b), (c), 0, 0, 0)

// ---------------- workspace layout (bytes, 64B-aligned) ----------------
#define OFF_OFFS  0u             // (N_NODES+1) ints
#define OFF_BHT   400064u        // NBUCKET ints (bucket totals)
#define OFF_BST   401664u        // NBUCKET+1 ints (bucket starts)
#define OFF_GCUR  403264u        // NBUCKET ints (bucket cursors)
#define OFF_BLKH  404864u        // P1GRID*NBUCKET ints (per-block bucket hist)
#define OFF_ESRC  1016448u       // N_EDGES ints
#define OFF_PAIR  7416448u       // N_EDGES u32 packed (src<<8 | d&255)
#define OFF_X16   13816448u      // N_PAD*DIM f16
#define OFF_A16   39424640u      // N_PAD*DIM f16
#define OFF_B16   65032832u      // N_PAD*DIM f16
#define OFF_W1T   90641024u      // 3*128*128 f16 ([l][n][k])
#define OFF_W2T   90739328u      // 3*128*128 f16
// end ~90.8 MB

// ---------------- CSR build: bucket partition (4 kernels, proven) ----------------

__global__ __launch_bounds__(256) void k_bhist(const int* __restrict__ dst,
                                               int* __restrict__ btot, int* __restrict__ blkh) {
    __shared__ int h[NBUCKET];
    int tid = threadIdx.x, b = blockIdx.x;
    for (int i = tid; i < NBUCKET; i += 256) h[i] = 0;
    __syncthreads();
    int base = b * P1CHUNK;
    int n = min(P1CHUNK, N_EDGES - base);
    for (int i = tid; i < n; i += 256)
        atomicAdd(&h[dst[base + i] >> BSHIFT], 1);
    __syncthreads();
    for (int i = tid; i < NBUCKET; i += 256) {
        blkh[b * NBUCKET + i] = h[i];
        atomicAdd(&btot[i], h[i]);
    }
}

// 1-block parallel exclusive scan of btot[NBUCKET] (padded to 512)
__global__ __launch_bounds__(256) void k_bscan(const int* __restrict__ btot,
                                               int* __restrict__ bstart,
                                               int* __restrict__ gcursor,
                                               int* __restrict__ offs) {
    __shared__ int s[512];
    int t = threadIdx.x;
    s[t]       = (t < NBUCKET) ? btot[t] : 0;
    s[t + 256] = (t + 256 < NBUCKET) ? btot[t + 256] : 0;
    __syncthreads();
    for (int off = 1; off < 512; off <<= 1) {
        int a0 = (t >= off) ? s[t - off] : 0;
        int a1 = (t + 256 >= off) ? s[t + 256 - off] : 0;
        __syncthreads();
        s[t] += a0; s[t + 256] += a1;
        __syncthreads();
    }
    int e0 = (t == 0) ? 0 : s[t - 1];     // exclusive starts
    int e1 = s[t + 255];
    if (t < NBUCKET) { bstart[t] = e0; gcursor[t] = e0; }
    int idx = t + 256;
    if (idx <= NBUCKET) { bstart[idx] = e1; if (idx < NBUCKET) gcursor[idx] = e1; }
    if (t == 0) offs[N_NODES] = N_EDGES;
}

__global__ __launch_bounds__(256) void k_part1(const int* __restrict__ src, const int* __restrict__ dst,
                                               const int* __restrict__ blkh, int* __restrict__ gcursor,
                                               uint32_t* __restrict__ pairs) {
    __shared__ int gbase[NBUCKET];
    __shared__ int cur[NBUCKET];
    int tid = threadIdx.x, b = blockIdx.x;
    for (int i = tid; i < NBUCKET; i += 256) {
        int h = blkh[b * NBUCKET + i];
        gbase[i] = atomicAdd(&gcursor[i], h);
        cur[i] = 0;
    }
    __syncthreads();
    int base = b * P1CHUNK;
    int n = min(P1CHUNK, N_EDGES - base);
    for (int i = tid; i < n; i += 256) {
        int d = dst[base + i], s = src[base + i];
        int bin = d >> BSHIFT;
        int slot = atomicAdd(&cur[bin], 1);
        pairs[gbase[bin] + slot] = ((uint32_t)s << 8) | (uint32_t)(d & 255);
    }
}

__global__ __launch_bounds__(256) void k_part2(const uint32_t* __restrict__ pairs,
                                               const int* __restrict__ bstart,
                                               int* __restrict__ offs, int* __restrict__ esrc) {
    __shared__ int cnt[256];
    __shared__ int cur[256];
    __shared__ int sc[256];
    int t = threadIdx.x, b = blockIdx.x;
    int n0 = b << BSHIFT;
    int nn = min(256, N_NODES - n0);
    int e0 = bstart[b], e1 = bstart[b + 1];
    cnt[t] = 0;
    __syncthreads();
    for (int i = e0 + t; i < e1; i += 256)
        atomicAdd(&cnt[pairs[i] & 255], 1);
    __syncthreads();
    int my = cnt[t];
    sc[t] = my;
    __syncthreads();
    for (int off = 1; off < 256; off <<= 1) {
        int v = (t >= off) ? sc[t - off] : 0;
        __syncthreads();
        sc[t] += v;
        __syncthreads();
    }
    int excl = sc[t] - my;
    cur[t] = excl;
    if (t < nn) offs[n0 + t] = e0 + excl;
    __syncthreads();
    for (int i = e0 + t; i < e1; i += 256) {
        uint32_t p = pairs[i];
        int pos = e0 + atomicAdd(&cur[p & 255], 1);
        esrc[pos] = (int)(p >> 8);          // 16KB region, single block -> single XCD
    }
}

// ---------------- merged dtype conversion (x, W1, W2) ----------------

#define CVTX_BLOCKS 6250         // N_NODES*DIM/8/256

__global__ void k_cvt(const float* __restrict__ x,
                      const float* __restrict__ W1, const float* __restrict__ W2,
                      f16* __restrict__ x16, f16* __restrict__ W1t, f16* __restrict__ W2t) {
    int b = blockIdx.x;
    if (b < CVTX_BLOCKS) {
        size_t i = ((size_t)b * 256 + threadIdx.x) * 8;
        float4 v0 = *(const float4*)&x[i];
        float4 v1 = *(const float4*)&x[i + 4];
        f16x8 h;
        h[0] = (f16)v0.x; h[1] = (f16)v0.y; h[2] = (f16)v0.z; h[3] = (f16)v0.w;
        h[4] = (f16)v1.x; h[5] = (f16)v1.y; h[6] = (f16)v1.z; h[7] = (f16)v1.w;
        *(f16x8*)&x16[i] = h;
    } else {
        int t = (b - CVTX_BLOCKS) * 256 + threadIdx.x;   // 98304 total
        bool first = t < 49152;
        const float* W = first ? W1 : W2;
        f16* Wt = first ? W1t : W2t;
        int u = first ? t : t - 49152;
        int l = u >> 14;
        int kn = u & 16383;
        int k = kn >> 7, nn = kn & 127;
        Wt[l * 16384 + nn * 128 + k] = (f16)W[u];
    }
}

// ---------------- fused layer: gather -> LDS tile -> MLP -> global / pool ----------------
// out = relu(relu((x_i + sum_j x_j) @ W1 + b1) @ W2 + b2)
// 512 threads (8 waves); wave w gathers 8 nodes (4 x 16-lane groups, 2 serial,
// 8-deep unroll), then owns 16 output columns in both GEMMs.
// POOL=true (layer 2): out-tile stays in LDS; segmented per-graph sums are
// atomically added into gsum instead of writing xout.

#define BM 64
#define LDS_K 136    // padded row stride in f16 (272 B)

template <bool POOL>
__global__ __launch_bounds__(512) void k_fused(
    const f16* __restrict__ xin, f16* __restrict__ xout,
    const int* __restrict__ offs, const int* __restrict__ esrc,
    const f16* __restrict__ W1t, const float* __restrict__ b1,
    const f16* __restrict__ W2t, const float* __restrict__ b2,
    const int* __restrict__ batch, float* __restrict__ gsum)
{
    __shared__ __align__(16) f16 tile[BM * LDS_K];
    __shared__ int sbatch[BM];
    int tid  = threadIdx.x;
    int lane = tid & 63;
    int w    = tid >> 6;          // wave 0..7
    int fr   = lane & 15;
    int fg   = lane >> 4;
    int row0 = blockIdx.x * BM;

    if (POOL && tid < BM) {
        int node = row0 + tid;
        sbatch[tid] = (node < N_NODES) ? batch[node] : -1;
    }

    // ---- gather phase: group fg of wave w owns nodes w*8 + b_*4 + fg
    {
        const f16x8* xr = (const f16x8*)xin;   // 16 x 16B chunks per row
        int c = fr;
#pragma unroll
        for (int b_ = 0; b_ < 2; b_++) {
            int r = w * 8 + b_ * 4 + fg;
            int node = row0 + r;
            f16x8 sum = {(f16)0, (f16)0, (f16)0, (f16)0, (f16)0, (f16)0, (f16)0, (f16)0};
            if (node < N_NODES) {
                sum = xr[(size_t)node * 16 + c];            // self term
                int e0 = offs[node], e1 = offs[node + 1];
                int e = e0;
                for (; e + 8 <= e1; e += 8) {
                    int s0 = esrc[e + 0], s1 = esrc[e + 1], s2 = esrc[e + 2], s3 = esrc[e + 3];
                    int s4 = esrc[e + 4], s5 = esrc[e + 5], s6 = esrc[e + 6], s7 = esrc[e + 7];
                    f16x8 v0 = xr[(size_t)s0 * 16 + c], v1 = xr[(size_t)s1 * 16 + c];
                    f16x8 v2 = xr[(size_t)s2 * 16 + c], v3 = xr[(size_t)s3 * 16 + c];
                    f16x8 v4 = xr[(size_t)s4 * 16 + c], v5 = xr[(size_t)s5 * 16 + c];
                    f16x8 v6 = xr[(size_t)s6 * 16 + c], v7 = xr[(size_t)s7 * 16 + c];
                    sum += (v0 + v1) + (v2 + v3);
                    sum += (v4 + v5) + (v6 + v7);
                }
                if (e < e1) {                               // masked remainder (<=7)
                    int i1 = e + 1, i2 = e + 2, i3 = e + 3, i4 = e + 4, i5 = e + 5, i6 = e + 6, i7 = e + 7;
                    bool k1 = i1 < e1, k2 = i2 < e1, k3 = i3 < e1, k4 = i4 < e1,
                         k5 = i5 < e1, k6 = i6 < e1, k7 = i7 < e1;
                    int s0 = esrc[e];
                    int s1 = esrc[k1 ? i1 : e], s2 = esrc[k2 ? i2 : e], s3 = esrc[k3 ? i3 : e];
                    int s4 = esrc[k4 ? i4 : e], s5 = esrc[k5 ? i5 : e], s6 = esrc[k6 ? i6 : e];
                    int s7 = esrc[k7 ? i7 : e];
                    f16x8 v0 = xr[(size_t)s0 * 16 + c], v1 = xr[(size_t)s1 * 16 + c];
                    f16x8 v2 = xr[(size_t)s2 * 16 + c], v3 = xr[(size_t)s3 * 16 + c];
                    f16x8 v4 = xr[(size_t)s4 * 16 + c], v5 = xr[(size_t)s5 * 16 + c];
                    f16x8 v6 = xr[(size_t)s6 * 16 + c], v7 = xr[(size_t)s7 * 16 + c];
                    sum += v0;
                    if (k1) sum += v1;
                    if (k2) sum += v2;
                    if (k3) sum += v3;
                    if (k4) sum += v4;
                    if (k5) sum += v5;
                    if (k6) sum += v6;
                    if (k7) sum += v7;
                }
            }
            *(f16x8*)&tile[r * LDS_K + c * 8] = sum;
        }
    }

    // W1 fragments + bias for this wave's 16 cols (overlaps gather of other waves)
    int col = w * 16 + fr;
    f16x8 wf[4];
    float4 bv;
#pragma unroll
    for (int ks = 0; ks < 4; ks++)
        wf[ks] = *(const f16x8*)&W1t[col * DIM + ks * 32 + fg * 8];
    bv = *(const float4*)&b1[w * 16 + fg * 4];
    __syncthreads();

    // ---- GEMM1 (swapped operands)
    f32x4 acc[4];
#pragma unroll
    for (int mt = 0; mt < 4; mt++) acc[mt] = (f32x4){0.f, 0.f, 0.f, 0.f};
#pragma unroll
    for (int mt = 0; mt < 4; mt++)
#pragma unroll
        for (int ks = 0; ks < 4; ks++) {
            f16x8 a = *(const f16x8*)&tile[(mt * 16 + fr) * LDS_K + ks * 32 + fg * 8];
            acc[mt] = MFMA16(wf[ks], a, acc[mt]);
        }
    __syncthreads();   // all X reads done before overwriting tile with H

    // H epilogue: relu(acc+b1) -> tile[node][feature], 8B vector writes
#pragma unroll
    for (int mt = 0; mt < 4; mt++) {
        f16x4 hv;
        hv[0] = (f16)fmaxf(acc[mt][0] + bv.x, 0.f);
        hv[1] = (f16)fmaxf(acc[mt][1] + bv.y, 0.f);
        hv[2] = (f16)fmaxf(acc[mt][2] + bv.z, 0.f);
        hv[3] = (f16)fmaxf(acc[mt][3] + bv.w, 0.f);
        *(f16x4*)&tile[(mt * 16 + fr) * LDS_K + w * 16 + fg * 4] = hv;
    }

    // reload fragments with W2/b2 (L2-hot), reuse registers
#pragma unroll
    for (int ks = 0; ks < 4; ks++)
        wf[ks] = *(const f16x8*)&W2t[col * DIM + ks * 32 + fg * 8];
    bv = *(const float4*)&b2[w * 16 + fg * 4];
    __syncthreads();   // H fully written

    // ---- GEMM2 (swapped)
#pragma unroll
    for (int mt = 0; mt < 4; mt++) acc[mt] = (f32x4){0.f, 0.f, 0.f, 0.f};
#pragma unroll
    for (int mt = 0; mt < 4; mt++)
#pragma unroll
        for (int ks = 0; ks < 4; ks++) {
            f16x8 a = *(const f16x8*)&tile[(mt * 16 + fr) * LDS_K + ks * 32 + fg * 8];
            acc[mt] = MFMA16(wf[ks], a, acc[mt]);
        }

    if (!POOL) {
        // store direct to global, 8B per lane
#pragma unroll
        for (int mt = 0; mt < 4; mt++) {
            f16x4 ov;
            ov[0] = (f16)fmaxf(acc[mt][0] + bv.x, 0.f);
            ov[1] = (f16)fmaxf(acc[mt][1] + bv.y, 0.f);
            ov[2] = (f16)fmaxf(acc[mt][2] + bv.z, 0.f);
            ov[3] = (f16)fmaxf(acc[mt][3] + bv.w, 0.f);
            *(f16x4*)&xout[(size_t)(row0 + mt * 16 + fr) * DIM + w * 16 + fg * 4] = ov;
        }
    } else {
        __syncthreads();   // all H reads done before overwriting tile with OUT
#pragma unroll
        for (int mt = 0; mt < 4; mt++) {
            f16x4 ov;
            ov[0] = (f16)fmaxf(acc[mt][0] + bv.x, 0.f);
            ov[1] = (f16)fmaxf(acc[mt][1] + bv.y, 0.f);
            ov[2] = (f16)fmaxf(acc[mt][2] + bv.z, 0.f);
            ov[3] = (f16)fmaxf(acc[mt][3] + bv.w, 0.f);
            *(f16x4*)&tile[(mt * 16 + fr) * LDS_K + w * 16 + fg * 4] = ov;
        }
        __syncthreads();   // out-tile fully written

        // segmented per-graph sums: 4 row-chunks of 16, 128 dims each
        int half = tid >> 7;               // 0..3
        int d = tid & 127;
        int rA = half * 16, rB = rA + 16;
        float s = 0.f;
        int curg = sbatch[rA];
        for (int r = rA; r < rB; r++) {
            int g = sbatch[r];
            if (g != curg) {
                if (curg >= 0) atomicAdd(&gsum[(size_t)curg * DIM + d], s);
                s = 0.f; curg = g;
            }
            if (g >= 0) s += (float)tile[r * LDS_K + d];
        }
        if (curg >= 0) atomicAdd(&gsum[(size_t)curg * DIM + d], s);
    }
}

// ---------------- final divide: out[g][d] /= count(g) ----------------

__global__ void k_div(float* __restrict__ out, const int* __restrict__ batch) {
    int g = blockIdx.x;
    int d = threadIdx.x;
    int lo = 0, hi = N_NODES;
    while (lo < hi) { int m = (lo + hi) >> 1; if (batch[m] < g) lo = m + 1; else hi = m; }
    int start = lo;
    hi = N_NODES;
    while (lo < hi) { int m = (lo + hi) >> 1; if (batch[m] <= g) lo = m + 1; else hi = m; }
    int end = lo;
    float cntf = (float)(end - start);
    out[(size_t)g * DIM + d] /= fmaxf(cntf, 1.f);
}

// ---------------- launch ----------------

extern "C" void kernel_launch(void* const* d_in, const int* in_sizes, int n_in,
                              void* d_out, int out_size, void* d_ws, size_t ws_size,
                              hipStream_t stream) {
    const float* x     = (const float*)d_in[0];
    const int*   ei    = (const int*)d_in[1];
    const int*   batch = (const int*)d_in[2];
    const float* W1    = (const float*)d_in[3];
    const float* b1    = (const float*)d_in[4];
    const float* W2    = (const float*)d_in[5];
    const float* b2    = (const float*)d_in[6];
    const int* srcp = ei;
    const int* dstp = ei + N_EDGES;

    char* ws = (char*)d_ws;
    int*      offs  = (int*)(ws + OFF_OFFS);
    int*      btot  = (int*)(ws + OFF_BHT);
    int*      bst   = (int*)(ws + OFF_BST);
    int*      gcur  = (int*)(ws + OFF_GCUR);
    int*      blkh  = (int*)(ws + OFF_BLKH);
    int*      esrc  = (int*)(ws + OFF_ESRC);
    uint32_t* pairs = (uint32_t*)(ws + OFF_PAIR);
    f16*      x16   = (f16*)(ws + OFF_X16);
    f16*      a16   = (f16*)(ws + OFF_A16);
    f16*      b16   = (f16*)(ws + OFF_B16);
    f16*      w1t   = (f16*)(ws + OFF_W1T);
    f16*      w2t   = (f16*)(ws + OFF_W2T);
    float*    outp  = (float*)d_out;

    // CSR build via bucket partition
    hipMemsetAsync(btot, 0, NBUCKET * sizeof(int), stream);
    k_bhist<<<P1GRID, 256, 0, stream>>>(dstp, btot, blkh);
    k_bscan<<<1, 256, 0, stream>>>(btot, bst, gcur, offs);
    k_part1<<<P1GRID, 256, 0, stream>>>(srcp, dstp, blkh, gcur, pairs);
    k_part2<<<NBUCKET, 256, 0, stream>>>(pairs, bst, offs, esrc);

    // conversions (x + both weight tensors, one launch)
    k_cvt<<<CVTX_BLOCKS + 384, 256, 0, stream>>>(x, W1, W2, x16, w1t, w2t);

    // zero graph-sum accumulator (pool folded into layer 2)
    hipMemsetAsync(outp, 0, (size_t)N_GRAPHS * DIM * sizeof(float), stream);

    // 3 fused GIN layers
    k_fused<false><<<N_PAD / BM, 512, 0, stream>>>(x16, a16, offs, esrc,
                                                   w1t, b1, w2t, b2, batch, outp);
    k_fused<false><<<N_PAD / BM, 512, 0, stream>>>(a16, b16, offs, esrc,
                                                   w1t + 16384, b1 + DIM, w2t + 16384, b2 + DIM, batch, outp);
    k_fused<true><<<N_PAD / BM, 512, 0, stream>>>(b16, a16, offs, esrc,
                                                  w1t + 32768, b1 + 2 * DIM, w2t + 32768, b2 + 2 * DIM, batch, outp);

    // divide by per-graph counts
    k_div<<<N_GRAPHS, DIM, 0, stream>>>(outp, batch);
}